// Round 7
// baseline (309.662 us; speedup 1.0000x reference)
//
#include <hip/hip_runtime.h>
#include <stdint.h>
#include <math.h>

// ---------------------------------------------------------------------------
// HardNegativeMiner round 17b: 64x64 tile -> halve per-thread register state
// -> 6 waves/SIMD. (Resubmit: container failed twice pre-launch, same infra
// flake as round 3; audit clean — bounds, swizzle inverse-pair, gum
// bijection, no deadlock path.)
// Evidence: r12-r16 all show VALUBusy*dur = 143-149 us (invariant busy floor);
// r12 (199 us) idles 28% and is hard-capped at 4 waves/SIMD: VGPR 64 + AGPR
// acc 32 + gum/frags => ~128 regs/thread. r14 proved budget<liveset spills;
// r16 proved in-window scheduling shuffles don't help (209). So: shrink the
// live set itself. 64x64 tile, 4 waves of 32x32: acc[2][2]=16, gum[16],
// frags 32 -> ~80 regs -> (256,6) budget 85 fits -> 6 waves/SIMD (+50% TLP
// to fill barrier/dep stalls). LDS exactly 16 KB (r15: 12KB rounds to 16).
// Same split-barrier K-loop, same swizzle (0 conflicts), same gumbel
// placement as r12 (after MFMAs; r16 showed pre-barrier2 placement hurts).
// Costs accepted: staging x1.33 (L2-served), atomics x2 (trivial rate).
// Spill guard: WRITE_SIZE must stay ~26 MB; jump => retry at (256,5).
// PRNG chain (partitionable threefry) verified bit-exact in rounds 1-16.
// ---------------------------------------------------------------------------
#define BN 16384   // batch
#define DK 256     // dim
#define NH 3276    // int(16384*0.2)
#define NJB 52     // j-strips of 64 (52*64 = 3328 >= NH)
#define NCB 256    // c-tiles of 64
#define NTILE (NJB * NCB)   // 13312 = 8 * 1664

typedef __attribute__((ext_vector_type(8))) short short8;
typedef __attribute__((ext_vector_type(4))) short short4v;
typedef __attribute__((ext_vector_type(4))) float f32x4;

__host__ __device__ __forceinline__ void tf2x32(uint32_t k0, uint32_t k1,
                                                uint32_t c0, uint32_t c1,
                                                uint32_t& o0, uint32_t& o1) {
  uint32_t ks2 = 0x1BD11BDAu ^ k0 ^ k1;
  uint32_t x0 = c0 + k0, x1 = c1 + k1;
#define RR(d) { x0 += x1; x1 = __builtin_rotateleft32(x1, d); x1 ^= x0; }
  RR(13) RR(15) RR(26) RR(6)   x0 += k1;  x1 += ks2 + 1u;
  RR(17) RR(29) RR(16) RR(24)  x0 += ks2; x1 += k0  + 2u;
  RR(13) RR(15) RR(26) RR(6)   x0 += k0;  x1 += k1  + 3u;
  RR(17) RR(29) RR(16) RR(24)  x0 += k1;  x1 += ks2 + 4u;
  RR(13) RR(15) RR(26) RR(6)   x0 += ks2; x1 += k0  + 5u;
#undef RR
  o0 = x0; o1 = x1;
}

__device__ __forceinline__ uint32_t rand32_at(uint32_t k0, uint32_t k1, uint32_t p) {
  uint32_t x0, x1; tf2x32(k0, k1, 0u, p, x0, x1);
  return x0 ^ x1;
}

__device__ __forceinline__ float unif01_from_bits(uint32_t bits) {
  return __uint_as_float((bits >> 9) | 0x3f800000u) - 1.0f;
}

// gumbel at flat counter p: -log(-log(max(u, tiny))), fast v_log_f32 path
__device__ __forceinline__ float gumbel_at(uint32_t k0, uint32_t k1, uint32_t p) {
  uint32_t bits = rand32_at(k0, k1, p);
  float f = unif01_from_bits(bits);
  float u = fmaxf(f, 1.17549435e-38f);             // minval = finfo(f32).tiny
  float t = __log2f(u) * (-0.69314718055994531f);  // -ln(u) > 0
  return __log2f(t) * (-0.69314718055994531f);     // -ln(t)
}

// monotonic float->u32; pack (value, ~col): max => larger val, tie => smaller col
__device__ __forceinline__ unsigned long long packvc(float v, uint32_t c) {
  uint32_t u = __float_as_uint(v);
  u ^= ((int32_t)u < 0) ? 0xFFFFFFFFu : 0x80000000u;
  return ((unsigned long long)u << 32) | (unsigned long long)(~c);
}

// 16-byte global -> LDS async DMA. LDS dest is wave-uniform base + lane*16.
__device__ __forceinline__ void glds16(const unsigned short* g, short* l) {
  __builtin_amdgcn_global_load_lds(
      (const __attribute__((address_space(1))) void*)g,
      (__attribute__((address_space(3))) void*)l, 16, 0, 0);
}

// ---------------------------------------------------------------------------
// Fused: row inv-norm + split-bf16 copy of z*inv (GEMM acc == sim directly)
// + src_idx/best setup.
__global__ __launch_bounds__(256) void k_prep(const float* __restrict__ z,
                                              unsigned short* __restrict__ zh,
                                              unsigned short* __restrict__ zl,
                                              int* __restrict__ src_idx,
                                              unsigned long long* __restrict__ best,
                                              uint32_t k20, uint32_t k21) {
  int b = blockIdx.x, t = threadIdx.x;
  if (b < BN / 4) {
    int row = b * 4 + (t >> 6), lane = t & 63;
    float4 v = *(const float4*)&z[row * DK + lane * 4];
    float ss = v.x * v.x + v.y * v.y + v.z * v.z + v.w * v.w;
#pragma unroll
    for (int off = 32; off; off >>= 1) ss += __shfl_xor(ss, off, 64);
    float inv = 1.0f / fmaxf(sqrtf(ss), 1e-12f);
    float f[4] = {v.x * inv, v.y * inv, v.z * inv, v.w * inv};
    short4v h, l;
#pragma unroll
    for (int i = 0; i < 4; ++i) {
      uint32_t u = __float_as_uint(f[i]);
      h[i] = (short)(u >> 16);
      float r = f[i] - __uint_as_float(u & 0xFFFF0000u);
      l[i] = (short)(__float_as_uint(r) >> 16);
    }
    *(short4v*)&zh[row * DK + lane * 4] = h;
    *(short4v*)&zl[row * DK + lane * 4] = l;
  } else {
    int i = (b - BN / 4) * 256 + t;
    if (i < NH) {
      uint32_t bits = rand32_at(k20, k21, (uint32_t)i);
      src_idx[i] = (int)(bits & (uint32_t)(BN - 1));  // randint span 2^14
      best[i] = 0ull;                                 // identity for packvc keys
    }
  }
}

// ---------------------------------------------------------------------------
// 64x64 tile, 4 waves of 32x32. K=256 in 8 chunks of 32, split-barrier
// pipelined: barrier1 (DMA landed) -> ds_read frags -> barrier2 (LDS free) ->
// issue next chunk's DMA -> 12 MFMAs -> 2 pinned gumbels.
// LDS rows of 32 shorts; 16B unit u stored at u ^ ((row>>1)&3); DMA source
// addresses carry the inverse swizzle (r12 scheme, 0 conflicts verified).
__global__ __launch_bounds__(256, 6) void k_main(const unsigned short* __restrict__ zh,
                                                 const unsigned short* __restrict__ zl,
                                                 const int* __restrict__ src_idx,
                                                 unsigned long long* __restrict__ best,
                                                 uint32_t kt0, uint32_t kt1) {
  __shared__ __align__(16) short As_hi[64 * 32];    // 4 KB
  __shared__ __align__(16) short As_lo[64 * 32];    // 4 KB
  __shared__ __align__(16) short Bs_hi[64 * 32];    // 4 KB
  __shared__ __align__(16) short Bs_lo[64 * 32];    // 4 KB  -> 16 KB total

  // XCD-aware swizzle: XCD x owns c-tiles [32x, 32x+32) -> 2 MB B-set per L2
  const int flat = blockIdx.x;                 // 13312 = 8 * (32 * 52)
  const int xcd = flat & 7, slot = flat >> 3;  // slot in [0, 1664)
  const int c_base = (xcd * 32 + (slot & 31)) * 64;
  const int j_base = (slot >> 5) * 64;

  const int t = threadIdx.x;
  const int lane = t & 63, w = t >> 6;

  // staging: thread t covers row rs = t>>2 (A and B), data unit u (swizzled)
  const int rs = t >> 2;
  const int u = (t & 3) ^ ((rs >> 1) & 3);
  const uint32_t offA = (uint32_t)(src_idx[min(j_base + rs, NH - 1)] * DK + u * 8);
  const uint32_t offB = (uint32_t)((c_base + rs) * DK + u * 8);
  short* dA  = &As_hi[w * 512];   // lane writes at +lane*16B == t*8 shorts
  short* dAl = &As_lo[w * 512];
  short* dB  = &Bs_hi[w * 512];
  short* dBl = &Bs_lo[w * 512];

  // fragment roles: wave covers m-half mh (32 rows) x c-half ch (32 cols)
  const int mh = w >> 1, ch = w & 1;
  const int cl = lane & 15, q = lane >> 4;
  int foffA[2], foffB[2];
#pragma unroll
  for (int i = 0; i < 2; ++i) {
    int rA = mh * 32 + cl + i * 16;
    foffA[i] = rA * 32 + (q ^ ((rA >> 1) & 3)) * 8;
    int rB = ch * 32 + cl + i * 16;
    foffB[i] = rB * 32 + (q ^ ((rB >> 1) & 3)) * 8;
  }

  // epilogue coordinates (needed for in-loop gumbel counters)
  const int q4 = q * 4;
  const int roff = j_base + mh * 32;
  const uint32_t ccl = (uint32_t)(c_base + ch * 32 + cl);

  f32x4 acc[2][2];
#pragma unroll
  for (int mt = 0; mt < 2; ++mt)
#pragma unroll
    for (int nt = 0; nt < 2; ++nt) acc[mt][nt] = (f32x4){0.f, 0.f, 0.f, 0.f};

  float gum[16];   // gum[(mt*4+r)*2+nt], filled 2 per K-chunk

  // prologue: DMA chunk 0
  glds16(zh + offA, dA);
  glds16(zl + offA, dAl);
  glds16(zh + offB, dB);
  glds16(zl + offB, dBl);

#pragma unroll
  for (int kc = 0; kc < 8; ++kc) {
    __syncthreads();   // barrier1: chunk kc's DMA landed (issued a phase ago)

    short8 ah[2], al[2], bh[2], bl[2];
#pragma unroll
    for (int i = 0; i < 2; ++i) {
      bh[i] = *(const short8*)&Bs_hi[foffB[i]];
      bl[i] = *(const short8*)&Bs_lo[foffB[i]];
      ah[i] = *(const short8*)&As_hi[foffA[i]];
      al[i] = *(const short8*)&As_lo[foffA[i]];
    }
    __syncthreads();   // barrier2: all waves read LDS; safe to overwrite

    if (kc < 7) {      // issue chunk kc+1's DMA; lands during MFMA+gumbels
      const int ko = (kc + 1) * 32;
      glds16(zh + offA + ko, dA);
      glds16(zl + offA + ko, dAl);
      glds16(zh + offB + ko, dB);
      glds16(zl + offB + ko, dBl);
    }

#pragma unroll
    for (int mt = 0; mt < 2; ++mt)
#pragma unroll
      for (int nt = 0; nt < 2; ++nt) {
        acc[mt][nt] = __builtin_amdgcn_mfma_f32_16x16x32_bf16(ah[mt], bh[nt], acc[mt][nt], 0, 0, 0);
        acc[mt][nt] = __builtin_amdgcn_mfma_f32_16x16x32_bf16(ah[mt], bl[nt], acc[mt][nt], 0, 0, 0);
        acc[mt][nt] = __builtin_amdgcn_mfma_f32_16x16x32_bf16(al[mt], bh[nt], acc[mt][nt], 0, 0, 0);
      }

    // ---- 2 in-loop gumbels (idx = kc*2, kc*2+1); single pin per pair so the
    // two threefry chains interleave; pinned here to co-issue with MFMA/DMA.
    float gv0, gv1;
    {
      const int idx = kc * 2 + 0;
      const int mt = idx >> 3, r = (idx >> 1) & 3, nt = idx & 1;
      int gj = roff + mt * 16 + q4 + r;
      uint32_t p = (uint32_t)gj * (uint32_t)BN + ccl + (uint32_t)(nt * 16);
      gv0 = gumbel_at(kt0, kt1, p);
    }
    {
      const int idx = kc * 2 + 1;
      const int mt = idx >> 3, r = (idx >> 1) & 3, nt = idx & 1;
      int gj = roff + mt * 16 + q4 + r;
      uint32_t p = (uint32_t)gj * (uint32_t)BN + ccl + (uint32_t)(nt * 16);
      gv1 = gumbel_at(kt0, kt1, p);
    }
    asm volatile("" : "+v"(gv0), "+v"(gv1));
    gum[kc * 2 + 0] = gv0;
    gum[kc * 2 + 1] = gv1;
  }

  // ---- lean epilogue: tot = fmaf(sim,10,gum); argmax over wave's 32 cols ----
#pragma unroll
  for (int mt = 0; mt < 2; ++mt)
#pragma unroll
    for (int r = 0; r < 4; ++r) {
      int gj = roff + mt * 16 + q4 + r;
      int s = src_idx[min(gj, NH - 1)];
      float bv = -INFINITY; uint32_t bc = 0;
#pragma unroll
      for (int nt = 0; nt < 2; ++nt) {
        uint32_t c = ccl + (uint32_t)(nt * 16);
        float tot = fmaf(acc[mt][nt][r], 10.0f, gum[(mt * 4 + r) * 2 + nt]);
        tot = ((int)c == s) ? -INFINITY : tot;         // diagonal mask
        if (tot > bv) { bv = tot; bc = c; }
      }
      unsigned long long key = packvc(bv, bc);
#pragma unroll
      for (int off = 1; off <= 8; off <<= 1) {        // reduce over 16 cl lanes
        unsigned long long o = __shfl_xor(key, off, 64);
        if (o > key) key = o;
      }
      if (cl == 0 && gj < NH) atomicMax(&best[gj], key);
    }
}

__global__ __launch_bounds__(64) void k_out(const float* __restrict__ z,
                                            const int* __restrict__ src_idx,
                                            const unsigned long long* __restrict__ best,
                                            float* __restrict__ out,
                                            uint32_t ka0, uint32_t ka1) {
  int j = blockIdx.x;
  int lane = threadIdx.x;
  int s = src_idx[j];
  int tgt = (int)(~((uint32_t)(best[j] & 0xFFFFFFFFull)));
  uint32_t bits = rand32_at(ka0, ka1, (uint32_t)j);
  float alpha = unif01_from_bits(bits) * 0.5f;   // uniform * MIX_ALPHA
  float om = 1.0f - alpha;
  float4 a = *(const float4*)&z[s * DK + lane * 4];
  float4 b = *(const float4*)&z[tgt * DK + lane * 4];
  float4 o;
  o.x = alpha * a.x + om * b.x;
  o.y = alpha * a.y + om * b.y;
  o.z = alpha * a.z + om * b.z;
  o.w = alpha * a.w + om * b.w;
  *(float4*)&out[j * DK + lane * 4] = o;
}

// ---------------------------------------------------------------------------
extern "C" void kernel_launch(void* const* d_in, const int* in_sizes, int n_in,
                              void* d_out, int out_size, void* d_ws, size_t ws_size,
                              hipStream_t stream) {
  const float* z = (const float*)d_in[0];
  float* out = (float*)d_out;
  char* ws = (char*)d_ws;
  // ws layout (~16.8 MB):
  int*                src_idx = (int*)(ws);                        // 16 KB
  unsigned long long* best    = (unsigned long long*)(ws + 16384); // 32 KB
  unsigned short*     zh      = (unsigned short*)(ws + 65536);     // 8.39 MB
  unsigned short*     zl      = (unsigned short*)(ws + 65536 + 8388608);

  // host-side threefry key derivation (partitionable scheme, verified round 1)
  uint32_t r0 = 0u, r1 = 42u;
  uint32_t ks0, ks1, kt0, kt1, ka0, ka1, k20, k21;
  tf2x32(r0, r1, 0u, 0u, ks0, ks1);   // k_src   = split(root,3)[0]
  tf2x32(r0, r1, 0u, 1u, kt0, kt1);   // k_tgt   = split(root,3)[1]
  tf2x32(r0, r1, 0u, 2u, ka0, ka1);   // k_alpha = split(root,3)[2]
  tf2x32(ks0, ks1, 0u, 1u, k20, k21); // split(k_src,2)[1] (randint lower bits)

  k_prep<<<dim3(BN / 4 + (NH + 255) / 256), dim3(256), 0, stream>>>(
      z, zh, zl, src_idx, best, k20, k21);
  k_main<<<dim3(NTILE), dim3(256), 0, stream>>>(zh, zl, src_idx, best, kt0, kt1);
  k_out <<<dim3(NH), dim3(64), 0, stream>>>(z, src_idx, best, out, ka0, ka1);
}

// Round 8
// 281.926 us; speedup vs baseline: 1.0984x; 1.0984x over previous
//
#include <hip/hip_runtime.h>
#include <stdint.h>
#include <math.h>

// ---------------------------------------------------------------------------
// HardNegativeMiner round 18: r12 geometry + double-buffered LDS -> ONE
// barrier per K-chunk (8 drains/block vs 16), DMA issued right after the
// barrier into the idle buffer (full-phase in-flight window).
// Evidence: r13/r15/r17 proved occupancy/TLP is NOT binding (r17: occ 67%,
// 29% SLOWER; stall scales with per-chunk fixed costs). Derived counters
// overstate VALUBusy ~2x (gfx94x 4-cyc formula vs CDNA4 2-cyc SIMD-32);
// true r12 VALU-busy ~35% -> majority of wall time is sync/latency around
// the 16 barrier drains. This round halves them and decouples DMA landing
// from the read phase. Cost: 48 KB LDS -> 3 blocks/CU (proven non-binding).
// WAR safety: phase-k reads buf p, phase-k DMA writes buf p^1; reads drain
// at the next barrier before p is rewritten. Arithmetic bit-identical to
// r12 (same tile map, swizzle, gumbel counters/order, epilogue).
// PRNG chain (partitionable threefry) verified bit-exact in rounds 1-17.
// ---------------------------------------------------------------------------
#define BN 16384   // batch
#define DK 256     // dim
#define NH 3276    // int(16384*0.2)
#define NJB 52     // j-strips of 64 (52*64 = 3328 >= NH)
#define NCB 128    // c-blocks of 128
#define NTILE (NJB * NCB)   // 6656 = 8 * 832

typedef __attribute__((ext_vector_type(8))) short short8;
typedef __attribute__((ext_vector_type(4))) short short4v;
typedef __attribute__((ext_vector_type(4))) float f32x4;

__host__ __device__ __forceinline__ void tf2x32(uint32_t k0, uint32_t k1,
                                                uint32_t c0, uint32_t c1,
                                                uint32_t& o0, uint32_t& o1) {
  uint32_t ks2 = 0x1BD11BDAu ^ k0 ^ k1;
  uint32_t x0 = c0 + k0, x1 = c1 + k1;
#define RR(d) { x0 += x1; x1 = __builtin_rotateleft32(x1, d); x1 ^= x0; }
  RR(13) RR(15) RR(26) RR(6)   x0 += k1;  x1 += ks2 + 1u;
  RR(17) RR(29) RR(16) RR(24)  x0 += ks2; x1 += k0  + 2u;
  RR(13) RR(15) RR(26) RR(6)   x0 += k0;  x1 += k1  + 3u;
  RR(17) RR(29) RR(16) RR(24)  x0 += k1;  x1 += ks2 + 4u;
  RR(13) RR(15) RR(26) RR(6)   x0 += ks2; x1 += k0  + 5u;
#undef RR
  o0 = x0; o1 = x1;
}

__device__ __forceinline__ uint32_t rand32_at(uint32_t k0, uint32_t k1, uint32_t p) {
  uint32_t x0, x1; tf2x32(k0, k1, 0u, p, x0, x1);
  return x0 ^ x1;
}

__device__ __forceinline__ float unif01_from_bits(uint32_t bits) {
  return __uint_as_float((bits >> 9) | 0x3f800000u) - 1.0f;
}

// gumbel at flat counter p: -log(-log(max(u, tiny))), fast v_log_f32 path
__device__ __forceinline__ float gumbel_at(uint32_t k0, uint32_t k1, uint32_t p) {
  uint32_t bits = rand32_at(k0, k1, p);
  float f = unif01_from_bits(bits);
  float u = fmaxf(f, 1.17549435e-38f);             // minval = finfo(f32).tiny
  float t = __log2f(u) * (-0.69314718055994531f);  // -ln(u) > 0
  return __log2f(t) * (-0.69314718055994531f);     // -ln(t)
}

// monotonic float->u32; pack (value, ~col): max => larger val, tie => smaller col
__device__ __forceinline__ unsigned long long packvc(float v, uint32_t c) {
  uint32_t u = __float_as_uint(v);
  u ^= ((int32_t)u < 0) ? 0xFFFFFFFFu : 0x80000000u;
  return ((unsigned long long)u << 32) | (unsigned long long)(~c);
}

// 16-byte global -> LDS async DMA. LDS dest is wave-uniform base + lane*16.
__device__ __forceinline__ void glds16(const unsigned short* g, short* l) {
  __builtin_amdgcn_global_load_lds(
      (const __attribute__((address_space(1))) void*)g,
      (__attribute__((address_space(3))) void*)l, 16, 0, 0);
}

// ---------------------------------------------------------------------------
// Fused: row inv-norm + split-bf16 copy of z*inv (GEMM acc == sim directly)
// + src_idx/best setup.
__global__ __launch_bounds__(256) void k_prep(const float* __restrict__ z,
                                              unsigned short* __restrict__ zh,
                                              unsigned short* __restrict__ zl,
                                              int* __restrict__ src_idx,
                                              unsigned long long* __restrict__ best,
                                              uint32_t k20, uint32_t k21) {
  int b = blockIdx.x, t = threadIdx.x;
  if (b < BN / 4) {
    int row = b * 4 + (t >> 6), lane = t & 63;
    float4 v = *(const float4*)&z[row * DK + lane * 4];
    float ss = v.x * v.x + v.y * v.y + v.z * v.z + v.w * v.w;
#pragma unroll
    for (int off = 32; off; off >>= 1) ss += __shfl_xor(ss, off, 64);
    float inv = 1.0f / fmaxf(sqrtf(ss), 1e-12f);
    float f[4] = {v.x * inv, v.y * inv, v.z * inv, v.w * inv};
    short4v h, l;
#pragma unroll
    for (int i = 0; i < 4; ++i) {
      uint32_t u = __float_as_uint(f[i]);
      h[i] = (short)(u >> 16);
      float r = f[i] - __uint_as_float(u & 0xFFFF0000u);
      l[i] = (short)(__float_as_uint(r) >> 16);
    }
    *(short4v*)&zh[row * DK + lane * 4] = h;
    *(short4v*)&zl[row * DK + lane * 4] = l;
  } else {
    int i = (b - BN / 4) * 256 + t;
    if (i < NH) {
      uint32_t bits = rand32_at(k20, k21, (uint32_t)i);
      src_idx[i] = (int)(bits & (uint32_t)(BN - 1));  // randint span 2^14
      best[i] = 0ull;                                 // identity for packvc keys
    }
  }
}

// ---------------------------------------------------------------------------
// 64x128 tile, 4 waves of 32x64. K=256 in 8 chunks of 32, DOUBLE-BUFFERED:
// one __syncthreads per chunk. Phase kc: barrier (chunk kc's DMA landed in
// buf p; buf p^1 free) -> issue chunk kc+1 DMA into buf p^1 -> ds_read frags
// from buf p -> 24 MFMAs -> 4 pinned gumbels.
// LDS rows of 32 shorts; 16B unit u stored at u ^ ((row>>1)&3); DMA source
// addresses carry the inverse swizzle (0 conflicts verified r12).
__global__ __launch_bounds__(256, 4) void k_main(const unsigned short* __restrict__ zh,
                                                 const unsigned short* __restrict__ zl,
                                                 const int* __restrict__ src_idx,
                                                 unsigned long long* __restrict__ best,
                                                 uint32_t kt0, uint32_t kt1) {
  __shared__ __align__(16) short As_hi[2][64 * 32];    // 2 x 4 KB
  __shared__ __align__(16) short As_lo[2][64 * 32];    // 2 x 4 KB
  __shared__ __align__(16) short Bs_hi[2][128 * 32];   // 2 x 8 KB
  __shared__ __align__(16) short Bs_lo[2][128 * 32];   // 2 x 8 KB -> 48 KB

  // XCD-aware swizzle: XCD x owns c-blocks [16x, 16x+16) -> 2 MB B-set per L2
  const int flat = blockIdx.x;                 // 6656 = 8 * (16 * 52)
  const int xcd = flat & 7, slot = flat >> 3;  // slot in [0, 832)
  const int c_base = (xcd * 16 + (slot & 15)) * 128;
  const int j_base = (slot >> 4) * 64;

  const int t = threadIdx.x;
  const int lane = t & 63, w = t >> 6;

  // staging: wave w DMAs A rows [16w,16w+16) and B rows [32w,32w+32)
  const int ra = w * 16 + (lane >> 2);           // A row
  const int rb0 = w * 32 + (lane >> 2);          // B rows rb0, rb0+16
  const int rb1 = rb0 + 16;
  const int ua = (lane & 3) ^ ((ra >> 1) & 3);   // swizzle-inverted data unit
  const int ub0 = (lane & 3) ^ ((rb0 >> 1) & 3);
  const int ub1 = (lane & 3) ^ ((rb1 >> 1) & 3);
  const uint32_t offA = (uint32_t)(src_idx[min(j_base + ra, NH - 1)] * DK + ua * 8);
  const uint32_t offB0 = (uint32_t)((c_base + rb0) * DK + ub0 * 8);
  const uint32_t offB1 = (uint32_t)((c_base + rb1) * DK + ub1 * 8);

  // fragment roles: wave covers m-half mh (32 rows) x c-half ch (64 cols)
  const int mh = w >> 1, ch = w & 1;
  const int cl = lane & 15, q = lane >> 4;
  int foffA[2], foffB[4];
#pragma unroll
  for (int i = 0; i < 2; ++i) {
    int r = mh * 32 + cl + i * 16;
    foffA[i] = r * 32 + (q ^ ((r >> 1) & 3)) * 8;
  }
#pragma unroll
  for (int i = 0; i < 4; ++i) {
    int r = ch * 64 + cl + i * 16;
    foffB[i] = r * 32 + (q ^ ((r >> 1) & 3)) * 8;
  }

  // epilogue coordinates (needed for in-loop gumbel counters)
  const int q4 = q * 4;
  const int coff = c_base + ch * 64;
  const int roff = j_base + mh * 32;
  const uint32_t ccl = (uint32_t)(coff + cl);

  f32x4 acc[2][4];
#pragma unroll
  for (int mt = 0; mt < 2; ++mt)
#pragma unroll
    for (int nt = 0; nt < 4; ++nt) acc[mt][nt] = (f32x4){0.f, 0.f, 0.f, 0.f};

  float gum[32];   // gum[((mt*4+r)*4)+nt], filled 4 per K-chunk

  // stage chunk (ko = chunk*32 shorts) into buffer parity p
#define STAGE(ko, p)                                      \
  {                                                       \
    glds16(zh + offA + (ko), &As_hi[p][w * 512]);         \
    glds16(zl + offA + (ko), &As_lo[p][w * 512]);         \
    glds16(zh + offB0 + (ko), &Bs_hi[p][w * 1024]);       \
    glds16(zh + offB1 + (ko), &Bs_hi[p][w * 1024 + 512]); \
    glds16(zl + offB0 + (ko), &Bs_lo[p][w * 1024]);       \
    glds16(zl + offB1 + (ko), &Bs_lo[p][w * 1024 + 512]); \
  }

  // prologue: DMA chunk 0 -> buf 0
  STAGE(0, 0)

#pragma unroll
  for (int kc = 0; kc < 8; ++kc) {
    const int p = kc & 1;
    __syncthreads();   // chunk kc landed in buf p; buf p^1 free (reads drained)

    if (kc < 7) STAGE((kc + 1) * 32, p ^ 1)   // full-phase in-flight window

    short8 ah[2], al[2], bh[4], bl[4];
#pragma unroll
    for (int nt = 0; nt < 4; ++nt) {
      bh[nt] = *(const short8*)&Bs_hi[p][foffB[nt]];
      bl[nt] = *(const short8*)&Bs_lo[p][foffB[nt]];
    }
#pragma unroll
    for (int mt = 0; mt < 2; ++mt) {
      ah[mt] = *(const short8*)&As_hi[p][foffA[mt]];
      al[mt] = *(const short8*)&As_lo[p][foffA[mt]];
    }

#pragma unroll
    for (int mt = 0; mt < 2; ++mt)
#pragma unroll
      for (int nt = 0; nt < 4; ++nt) {
        acc[mt][nt] = __builtin_amdgcn_mfma_f32_16x16x32_bf16(ah[mt], bh[nt], acc[mt][nt], 0, 0, 0);
        acc[mt][nt] = __builtin_amdgcn_mfma_f32_16x16x32_bf16(ah[mt], bl[nt], acc[mt][nt], 0, 0, 0);
        acc[mt][nt] = __builtin_amdgcn_mfma_f32_16x16x32_bf16(al[mt], bh[nt], acc[mt][nt], 0, 0, 0);
      }

    // ---- interleaved gumbel generation: 4 of 32 per-thread gumbels ----
    // asm pin forces materialization here so the threefry VALU chain
    // co-issues with the MFMA latency above / DMA in flight.
#pragma unroll
    for (int i = 0; i < 4; ++i) {
      const int idx = kc * 4 + i;
      const int mt = idx >> 4, r = (idx >> 2) & 3, nt = idx & 3;
      int gj = roff + mt * 16 + q4 + r;
      uint32_t p2 = (uint32_t)gj * (uint32_t)BN + ccl + (uint32_t)(nt * 16);
      float gv = gumbel_at(kt0, kt1, p2);
      asm volatile("" : "+v"(gv));
      gum[idx] = gv;
    }
  }
#undef STAGE

  // ---- lean epilogue: tot = fmaf(sim,10,gum); argmax over wave's 64 cols ----
#pragma unroll
  for (int mt = 0; mt < 2; ++mt)
#pragma unroll
    for (int r = 0; r < 4; ++r) {
      int gj = roff + mt * 16 + q4 + r;
      int s = src_idx[min(gj, NH - 1)];
      float bv = -INFINITY; uint32_t bc = 0;
#pragma unroll
      for (int nt = 0; nt < 4; ++nt) {
        uint32_t c = ccl + (uint32_t)(nt * 16);
        float tot = fmaf(acc[mt][nt][r], 10.0f, gum[((mt * 4 + r) * 4) + nt]);
        tot = ((int)c == s) ? -INFINITY : tot;         // diagonal mask
        if (tot > bv) { bv = tot; bc = c; }
      }
      unsigned long long key = packvc(bv, bc);
#pragma unroll
      for (int off = 1; off <= 8; off <<= 1) {        // reduce over 16 cl lanes
        unsigned long long o = __shfl_xor(key, off, 64);
        if (o > key) key = o;
      }
      if (cl == 0 && gj < NH) atomicMax(&best[gj], key);
    }
}

__global__ __launch_bounds__(64) void k_out(const float* __restrict__ z,
                                            const int* __restrict__ src_idx,
                                            const unsigned long long* __restrict__ best,
                                            float* __restrict__ out,
                                            uint32_t ka0, uint32_t ka1) {
  int j = blockIdx.x;
  int lane = threadIdx.x;
  int s = src_idx[j];
  int tgt = (int)(~((uint32_t)(best[j] & 0xFFFFFFFFull)));
  uint32_t bits = rand32_at(ka0, ka1, (uint32_t)j);
  float alpha = unif01_from_bits(bits) * 0.5f;   // uniform * MIX_ALPHA
  float om = 1.0f - alpha;
  float4 a = *(const float4*)&z[s * DK + lane * 4];
  float4 b = *(const float4*)&z[tgt * DK + lane * 4];
  float4 o;
  o.x = alpha * a.x + om * b.x;
  o.y = alpha * a.y + om * b.y;
  o.z = alpha * a.z + om * b.z;
  o.w = alpha * a.w + om * b.w;
  *(float4*)&out[j * DK + lane * 4] = o;
}

// ---------------------------------------------------------------------------
extern "C" void kernel_launch(void* const* d_in, const int* in_sizes, int n_in,
                              void* d_out, int out_size, void* d_ws, size_t ws_size,
                              hipStream_t stream) {
  const float* z = (const float*)d_in[0];
  float* out = (float*)d_out;
  char* ws = (char*)d_ws;
  // ws layout (~16.8 MB):
  int*                src_idx = (int*)(ws);                        // 16 KB
  unsigned long long* best    = (unsigned long long*)(ws + 16384); // 32 KB
  unsigned short*     zh      = (unsigned short*)(ws + 65536);     // 8.39 MB
  unsigned short*     zl      = (unsigned short*)(ws + 65536 + 8388608);

  // host-side threefry key derivation (partitionable scheme, verified round 1)
  uint32_t r0 = 0u, r1 = 42u;
  uint32_t ks0, ks1, kt0, kt1, ka0, ka1, k20, k21;
  tf2x32(r0, r1, 0u, 0u, ks0, ks1);   // k_src   = split(root,3)[0]
  tf2x32(r0, r1, 0u, 1u, kt0, kt1);   // k_tgt   = split(root,3)[1]
  tf2x32(r0, r1, 0u, 2u, ka0, ka1);   // k_alpha = split(root,3)[2]
  tf2x32(ks0, ks1, 0u, 1u, k20, k21); // split(k_src,2)[1] (randint lower bits)

  k_prep<<<dim3(BN / 4 + (NH + 255) / 256), dim3(256), 0, stream>>>(
      z, zh, zl, src_idx, best, k20, k21);
  k_main<<<dim3(NTILE), dim3(256), 0, stream>>>(zh, zl, src_idx, best, kt0, kt1);
  k_out <<<dim3(NH), dim3(64), 0, stream>>>(z, src_idx, best, out, ka0, ka1);
}

// Round 9
// 268.866 us; speedup vs baseline: 1.1517x; 1.0486x over previous
//
#include <hip/hip_runtime.h>
#include <stdint.h>
#include <math.h>

// ---------------------------------------------------------------------------
// HardNegativeMiner round 19: r18 dbuf + PHASE MERGE — gumbels moved between
// ds_read issue and MFMA, fenced by sched_barrier(0) on both sides.
// Budget model (consistent r12-r18): per CU per chunk-generation VALU 2.6k,
// LDS 3.3k, MFMA 0.5k cyc; overlapped => ~4k/chunk (~100 us) but measured
// 9.2k (199 us): barrier-lockstep serializes LDS-phase (VALU idle) then
// VALU-phase (LDS idle). Merge needs (a) dbuf so no read-drain barrier sits
// in the read path (single-buffer barrier2 forces lgkm(0) — r16 proved), and
// (b) program order reads->gumbels->waitcnt->MFMA so 656 cyc of threefry
// VALU covers read latency within the SAME wave (ILP; TLP proven unavailable
// in r13/r15/r17). r18 had (a) but not (b) -> 234. This adds (b).
// Occupancy 3 blocks/CU (48 KB LDS) accepted; ILP replaces TLP.
// Arithmetic bit-identical to r12/r18 (same counters, gum order, MFMA order).
// PRNG chain (partitionable threefry) verified bit-exact in rounds 1-18.
// ---------------------------------------------------------------------------
#define BN 16384   // batch
#define DK 256     // dim
#define NH 3276    // int(16384*0.2)
#define NJB 52     // j-strips of 64 (52*64 = 3328 >= NH)
#define NCB 128    // c-blocks of 128
#define NTILE (NJB * NCB)   // 6656 = 8 * 832

typedef __attribute__((ext_vector_type(8))) short short8;
typedef __attribute__((ext_vector_type(4))) short short4v;
typedef __attribute__((ext_vector_type(4))) float f32x4;

__host__ __device__ __forceinline__ void tf2x32(uint32_t k0, uint32_t k1,
                                                uint32_t c0, uint32_t c1,
                                                uint32_t& o0, uint32_t& o1) {
  uint32_t ks2 = 0x1BD11BDAu ^ k0 ^ k1;
  uint32_t x0 = c0 + k0, x1 = c1 + k1;
#define RR(d) { x0 += x1; x1 = __builtin_rotateleft32(x1, d); x1 ^= x0; }
  RR(13) RR(15) RR(26) RR(6)   x0 += k1;  x1 += ks2 + 1u;
  RR(17) RR(29) RR(16) RR(24)  x0 += ks2; x1 += k0  + 2u;
  RR(13) RR(15) RR(26) RR(6)   x0 += k0;  x1 += k1  + 3u;
  RR(17) RR(29) RR(16) RR(24)  x0 += k1;  x1 += ks2 + 4u;
  RR(13) RR(15) RR(26) RR(6)   x0 += ks2; x1 += k0  + 5u;
#undef RR
  o0 = x0; o1 = x1;
}

__device__ __forceinline__ uint32_t rand32_at(uint32_t k0, uint32_t k1, uint32_t p) {
  uint32_t x0, x1; tf2x32(k0, k1, 0u, p, x0, x1);
  return x0 ^ x1;
}

__device__ __forceinline__ float unif01_from_bits(uint32_t bits) {
  return __uint_as_float((bits >> 9) | 0x3f800000u) - 1.0f;
}

// gumbel at flat counter p: -log(-log(max(u, tiny))), fast v_log_f32 path
__device__ __forceinline__ float gumbel_at(uint32_t k0, uint32_t k1, uint32_t p) {
  uint32_t bits = rand32_at(k0, k1, p);
  float f = unif01_from_bits(bits);
  float u = fmaxf(f, 1.17549435e-38f);             // minval = finfo(f32).tiny
  float t = __log2f(u) * (-0.69314718055994531f);  // -ln(u) > 0
  return __log2f(t) * (-0.69314718055994531f);     // -ln(t)
}

// monotonic float->u32; pack (value, ~col): max => larger val, tie => smaller col
__device__ __forceinline__ unsigned long long packvc(float v, uint32_t c) {
  uint32_t u = __float_as_uint(v);
  u ^= ((int32_t)u < 0) ? 0xFFFFFFFFu : 0x80000000u;
  return ((unsigned long long)u << 32) | (unsigned long long)(~c);
}

// 16-byte global -> LDS async DMA. LDS dest is wave-uniform base + lane*16.
__device__ __forceinline__ void glds16(const unsigned short* g, short* l) {
  __builtin_amdgcn_global_load_lds(
      (const __attribute__((address_space(1))) void*)g,
      (__attribute__((address_space(3))) void*)l, 16, 0, 0);
}

// ---------------------------------------------------------------------------
// Fused: row inv-norm + split-bf16 copy of z*inv (GEMM acc == sim directly)
// + src_idx/best setup.
__global__ __launch_bounds__(256) void k_prep(const float* __restrict__ z,
                                              unsigned short* __restrict__ zh,
                                              unsigned short* __restrict__ zl,
                                              int* __restrict__ src_idx,
                                              unsigned long long* __restrict__ best,
                                              uint32_t k20, uint32_t k21) {
  int b = blockIdx.x, t = threadIdx.x;
  if (b < BN / 4) {
    int row = b * 4 + (t >> 6), lane = t & 63;
    float4 v = *(const float4*)&z[row * DK + lane * 4];
    float ss = v.x * v.x + v.y * v.y + v.z * v.z + v.w * v.w;
#pragma unroll
    for (int off = 32; off; off >>= 1) ss += __shfl_xor(ss, off, 64);
    float inv = 1.0f / fmaxf(sqrtf(ss), 1e-12f);
    float f[4] = {v.x * inv, v.y * inv, v.z * inv, v.w * inv};
    short4v h, l;
#pragma unroll
    for (int i = 0; i < 4; ++i) {
      uint32_t u = __float_as_uint(f[i]);
      h[i] = (short)(u >> 16);
      float r = f[i] - __uint_as_float(u & 0xFFFF0000u);
      l[i] = (short)(__float_as_uint(r) >> 16);
    }
    *(short4v*)&zh[row * DK + lane * 4] = h;
    *(short4v*)&zl[row * DK + lane * 4] = l;
  } else {
    int i = (b - BN / 4) * 256 + t;
    if (i < NH) {
      uint32_t bits = rand32_at(k20, k21, (uint32_t)i);
      src_idx[i] = (int)(bits & (uint32_t)(BN - 1));  // randint span 2^14
      best[i] = 0ull;                                 // identity for packvc keys
    }
  }
}

// ---------------------------------------------------------------------------
// 64x128 tile, 4 waves of 32x64. K=256 in 8 chunks of 32, DOUBLE-BUFFERED,
// one __syncthreads per chunk. Phase kc: barrier (chunk kc landed in buf p,
// buf p^1 free) -> issue chunk kc+1 DMA into buf p^1 -> issue 12 ds_reads
// from buf p -> [sched fence] -> 4 gumbels (656 cyc VALU; read latency and
// LDS pipe hide underneath) -> [sched fence] -> lgkm wait -> 24 MFMAs.
// LDS rows of 32 shorts; 16B unit u stored at u ^ ((row>>1)&3); DMA source
// addresses carry the inverse swizzle (0 conflicts verified r12).
__global__ __launch_bounds__(256, 4) void k_main(const unsigned short* __restrict__ zh,
                                                 const unsigned short* __restrict__ zl,
                                                 const int* __restrict__ src_idx,
                                                 unsigned long long* __restrict__ best,
                                                 uint32_t kt0, uint32_t kt1) {
  __shared__ __align__(16) short As_hi[2][64 * 32];    // 2 x 4 KB
  __shared__ __align__(16) short As_lo[2][64 * 32];    // 2 x 4 KB
  __shared__ __align__(16) short Bs_hi[2][128 * 32];   // 2 x 8 KB
  __shared__ __align__(16) short Bs_lo[2][128 * 32];   // 2 x 8 KB -> 48 KB

  // XCD-aware swizzle: XCD x owns c-blocks [16x, 16x+16) -> 2 MB B-set per L2
  const int flat = blockIdx.x;                 // 6656 = 8 * (16 * 52)
  const int xcd = flat & 7, slot = flat >> 3;  // slot in [0, 832)
  const int c_base = (xcd * 16 + (slot & 15)) * 128;
  const int j_base = (slot >> 4) * 64;

  const int t = threadIdx.x;
  const int lane = t & 63, w = t >> 6;

  // staging: wave w DMAs A rows [16w,16w+16) and B rows [32w,32w+32)
  const int ra = w * 16 + (lane >> 2);           // A row
  const int rb0 = w * 32 + (lane >> 2);          // B rows rb0, rb0+16
  const int rb1 = rb0 + 16;
  const int ua = (lane & 3) ^ ((ra >> 1) & 3);   // swizzle-inverted data unit
  const int ub0 = (lane & 3) ^ ((rb0 >> 1) & 3);
  const int ub1 = (lane & 3) ^ ((rb1 >> 1) & 3);
  const uint32_t offA = (uint32_t)(src_idx[min(j_base + ra, NH - 1)] * DK + ua * 8);
  const uint32_t offB0 = (uint32_t)((c_base + rb0) * DK + ub0 * 8);
  const uint32_t offB1 = (uint32_t)((c_base + rb1) * DK + ub1 * 8);

  // fragment roles: wave covers m-half mh (32 rows) x c-half ch (64 cols)
  const int mh = w >> 1, ch = w & 1;
  const int cl = lane & 15, q = lane >> 4;
  int foffA[2], foffB[4];
#pragma unroll
  for (int i = 0; i < 2; ++i) {
    int r = mh * 32 + cl + i * 16;
    foffA[i] = r * 32 + (q ^ ((r >> 1) & 3)) * 8;
  }
#pragma unroll
  for (int i = 0; i < 4; ++i) {
    int r = ch * 64 + cl + i * 16;
    foffB[i] = r * 32 + (q ^ ((r >> 1) & 3)) * 8;
  }

  // epilogue coordinates (needed for in-loop gumbel counters)
  const int q4 = q * 4;
  const int coff = c_base + ch * 64;
  const int roff = j_base + mh * 32;
  const uint32_t ccl = (uint32_t)(coff + cl);

  f32x4 acc[2][4];
#pragma unroll
  for (int mt = 0; mt < 2; ++mt)
#pragma unroll
    for (int nt = 0; nt < 4; ++nt) acc[mt][nt] = (f32x4){0.f, 0.f, 0.f, 0.f};

  float gum[32];   // gum[((mt*4+r)*4)+nt], filled 4 per K-chunk

  // stage chunk (ko = chunk*32 shorts) into buffer parity p
#define STAGE(ko, p)                                      \
  {                                                       \
    glds16(zh + offA + (ko), &As_hi[p][w * 512]);         \
    glds16(zl + offA + (ko), &As_lo[p][w * 512]);         \
    glds16(zh + offB0 + (ko), &Bs_hi[p][w * 1024]);       \
    glds16(zh + offB1 + (ko), &Bs_hi[p][w * 1024 + 512]); \
    glds16(zl + offB0 + (ko), &Bs_lo[p][w * 1024]);       \
    glds16(zl + offB1 + (ko), &Bs_lo[p][w * 1024 + 512]); \
  }

  // prologue: DMA chunk 0 -> buf 0
  STAGE(0, 0)

#pragma unroll
  for (int kc = 0; kc < 8; ++kc) {
    const int p = kc & 1;
    __syncthreads();   // chunk kc landed in buf p; buf p^1 free (reads drained)

    if (kc < 7) STAGE((kc + 1) * 32, p ^ 1)   // full-phase in-flight window

    short8 ah[2], al[2], bh[4], bl[4];
#pragma unroll
    for (int nt = 0; nt < 4; ++nt) {
      bh[nt] = *(const short8*)&Bs_hi[p][foffB[nt]];
      bl[nt] = *(const short8*)&Bs_lo[p][foffB[nt]];
    }
#pragma unroll
    for (int mt = 0; mt < 2; ++mt) {
      ah[mt] = *(const short8*)&As_hi[p][foffA[mt]];
      al[mt] = *(const short8*)&As_lo[p][foffA[mt]];
    }

    // fence: reads are ISSUED above; gumbels below may not move above this
    __builtin_amdgcn_sched_barrier(0);

    // ---- 4 gumbels: 656 cyc of independent threefry VALU sits between the
    // ds_read issue and the lgkm-wait before the MFMAs -> read latency and
    // LDS-pipe throughput hide under VALU within this wave.
#pragma unroll
    for (int i = 0; i < 4; ++i) {
      const int idx = kc * 4 + i;
      const int mt = idx >> 4, r = (idx >> 2) & 3, nt = idx & 3;
      int gj = roff + mt * 16 + q4 + r;
      uint32_t p2 = (uint32_t)gj * (uint32_t)BN + ccl + (uint32_t)(nt * 16);
      float gv = gumbel_at(kt0, kt1, p2);
      asm volatile("" : "+v"(gv));
      gum[idx] = gv;
    }

    // fence: MFMAs (and their lgkm wait) may not hoist above the gumbels
    __builtin_amdgcn_sched_barrier(0);

#pragma unroll
    for (int mt = 0; mt < 2; ++mt)
#pragma unroll
      for (int nt = 0; nt < 4; ++nt) {
        acc[mt][nt] = __builtin_amdgcn_mfma_f32_16x16x32_bf16(ah[mt], bh[nt], acc[mt][nt], 0, 0, 0);
        acc[mt][nt] = __builtin_amdgcn_mfma_f32_16x16x32_bf16(ah[mt], bl[nt], acc[mt][nt], 0, 0, 0);
        acc[mt][nt] = __builtin_amdgcn_mfma_f32_16x16x32_bf16(al[mt], bh[nt], acc[mt][nt], 0, 0, 0);
      }
  }
#undef STAGE

  // ---- lean epilogue: tot = fmaf(sim,10,gum); argmax over wave's 64 cols ----
#pragma unroll
  for (int mt = 0; mt < 2; ++mt)
#pragma unroll
    for (int r = 0; r < 4; ++r) {
      int gj = roff + mt * 16 + q4 + r;
      int s = src_idx[min(gj, NH - 1)];
      float bv = -INFINITY; uint32_t bc = 0;
#pragma unroll
      for (int nt = 0; nt < 4; ++nt) {
        uint32_t c = ccl + (uint32_t)(nt * 16);
        float tot = fmaf(acc[mt][nt][r], 10.0f, gum[((mt * 4 + r) * 4) + nt]);
        tot = ((int)c == s) ? -INFINITY : tot;         // diagonal mask
        if (tot > bv) { bv = tot; bc = c; }
      }
      unsigned long long key = packvc(bv, bc);
#pragma unroll
      for (int off = 1; off <= 8; off <<= 1) {        // reduce over 16 cl lanes
        unsigned long long o = __shfl_xor(key, off, 64);
        if (o > key) key = o;
      }
      if (cl == 0 && gj < NH) atomicMax(&best[gj], key);
    }
}

__global__ __launch_bounds__(64) void k_out(const float* __restrict__ z,
                                            const int* __restrict__ src_idx,
                                            const unsigned long long* __restrict__ best,
                                            float* __restrict__ out,
                                            uint32_t ka0, uint32_t ka1) {
  int j = blockIdx.x;
  int lane = threadIdx.x;
  int s = src_idx[j];
  int tgt = (int)(~((uint32_t)(best[j] & 0xFFFFFFFFull)));
  uint32_t bits = rand32_at(ka0, ka1, (uint32_t)j);
  float alpha = unif01_from_bits(bits) * 0.5f;   // uniform * MIX_ALPHA
  float om = 1.0f - alpha;
  float4 a = *(const float4*)&z[s * DK + lane * 4];
  float4 b = *(const float4*)&z[tgt * DK + lane * 4];
  float4 o;
  o.x = alpha * a.x + om * b.x;
  o.y = alpha * a.y + om * b.y;
  o.z = alpha * a.z + om * b.z;
  o.w = alpha * a.w + om * b.w;
  *(float4*)&out[j * DK + lane * 4] = o;
}

// ---------------------------------------------------------------------------
extern "C" void kernel_launch(void* const* d_in, const int* in_sizes, int n_in,
                              void* d_out, int out_size, void* d_ws, size_t ws_size,
                              hipStream_t stream) {
  const float* z = (const float*)d_in[0];
  float* out = (float*)d_out;
  char* ws = (char*)d_ws;
  // ws layout (~16.8 MB):
  int*                src_idx = (int*)(ws);                        // 16 KB
  unsigned long long* best    = (unsigned long long*)(ws + 16384); // 32 KB
  unsigned short*     zh      = (unsigned short*)(ws + 65536);     // 8.39 MB
  unsigned short*     zl      = (unsigned short*)(ws + 65536 + 8388608);

  // host-side threefry key derivation (partitionable scheme, verified round 1)
  uint32_t r0 = 0u, r1 = 42u;
  uint32_t ks0, ks1, kt0, kt1, ka0, ka1, k20, k21;
  tf2x32(r0, r1, 0u, 0u, ks0, ks1);   // k_src   = split(root,3)[0]
  tf2x32(r0, r1, 0u, 1u, kt0, kt1);   // k_tgt   = split(root,3)[1]
  tf2x32(r0, r1, 0u, 2u, ka0, ka1);   // k_alpha = split(root,3)[2]
  tf2x32(ks0, ks1, 0u, 1u, k20, k21); // split(k_src,2)[1] (randint lower bits)

  k_prep<<<dim3(BN / 4 + (NH + 255) / 256), dim3(256), 0, stream>>>(
      z, zh, zl, src_idx, best, k20, k21);
  k_main<<<dim3(NTILE), dim3(256), 0, stream>>>(zh, zl, src_idx, best, kt0, kt1);
  k_out <<<dim3(NH), dim3(64), 0, stream>>>(z, src_idx, best, out, ka0, ka1);
}